// Round 4
// baseline (147.953 us; speedup 1.0000x reference)
//
#include <hip/hip_runtime.h>
#include <hip/hip_bf16.h>
#include <cmath>

#define HW 262144          // 512*512
#define NC 16
#define NB 8
#define NSEG 16
#define SEGSZ (HW / NSEG)  // 16384
#define EPS 1e-5f

// ---------------- pass 1: per-(b,c,seg) partial sum & max ----------------
__global__ __launch_bounds__(256) void k_reduce(const float* __restrict__ x,
                                                float* __restrict__ psum,
                                                float* __restrict__ pmax) {
    int plane = blockIdx.x / NSEG;
    int seg   = blockIdx.x - plane * NSEG;
    const float4* p = reinterpret_cast<const float4*>(
        x + (size_t)plane * HW + (size_t)seg * SEGSZ);
    int t = threadIdx.x;
    float s = 0.0f, m = -INFINITY;
    #pragma unroll
    for (int it = 0; it < SEGSZ / (256 * 4); ++it) {
        float4 v = p[it * 256 + t];
        s += (v.x + v.y) + (v.z + v.w);
        m = fmaxf(m, fmaxf(fmaxf(v.x, v.y), fmaxf(v.z, v.w)));
    }
    #pragma unroll
    for (int off = 32; off > 0; off >>= 1) {
        s += __shfl_down(s, off, 64);
        m = fmaxf(m, __shfl_down(m, off, 64));
    }
    __shared__ float ls[4], lm[4];
    int wid = t >> 6, lane = t & 63;
    if (lane == 0) { ls[wid] = s; lm[wid] = m; }
    __syncthreads();
    if (t == 0) {
        psum[blockIdx.x] = (ls[0] + ls[1]) + (ls[2] + ls[3]);
        pmax[blockIdx.x] = fmaxf(fmaxf(lm[0], lm[1]), fmaxf(lm[2], lm[3]));
    }
}

// ---------------- pass 2: fold per-batch matrices ----------------
// params layout per batch (816 floats):
// [0:256)   A_T   (A[o][i] stored at i*16+o)
// [256:272) abias
// [272:528) G_T
// [528:544) gbias
// [544:800) W4_T  (W4[q][i] stored at i*16+q)
// [800:816) b4
__global__ __launch_bounds__(256) void k_params(
    const float* __restrict__ psum, const float* __restrict__ pmax,
    const float* __restrict__ Wc, const float* __restrict__ bc,
    const float* __restrict__ W1, const float* __restrict__ b1,
    const float* __restrict__ W2, const float* __restrict__ b2,
    const float* __restrict__ W3, const float* __restrict__ b3,
    const float* __restrict__ W4, const float* __restrict__ b4,
    float* __restrict__ params) {
    int b = blockIdx.x;
    int t = threadIdx.x;
    __shared__ float r2[NC], r4[NC], sWc[256], sW1[256], sW2[256], sW3[256];
    if (t < NC) {
        float s = 0.0f, m = -INFINITY;
        for (int k = 0; k < NSEG; ++k) {
            s += psum[(b * NC + t) * NSEG + k];
            m = fmaxf(m, pmax[(b * NC + t) * NSEG + k]);
        }
        r2[t] = 1.0f / (s * (1.0f / (float)HW) + EPS);
        r4[t] = 1.0f / (m + EPS);
    }
    sWc[t] = Wc[t]; sW1[t] = W1[t]; sW2[t] = W2[t]; sW3[t] = W3[t];
    __syncthreads();
    int o = t >> 4, i = t & 15;
    float accA = 0.0f, accG = 0.0f;
    #pragma unroll
    for (int c = 0; c < NC; ++c) {
        accA += sW2[o * NC + c] * r2[c] * sWc[c * NC + i];
        accG += sW3[o * NC + c] * r4[c] * sW1[c * NC + i];
    }
    float* P = params + b * 816;
    P[i * NC + o]       = accA;
    P[272 + i * NC + o] = accG;
    P[544 + i * NC + o] = W4[o * NC + i];
    if (i == 0) {
        float ba = 0.0f, bg = 0.0f;
        #pragma unroll
        for (int c = 0; c < NC; ++c) {
            ba += sW2[o * NC + c] * r2[c] * bc[c];
            bg += sW3[o * NC + c] * r4[c] * b1[c];
        }
        P[256 + o] = ba + b2[o];
        P[528 + o] = bg + b3[o];
        P[800 + o] = b4[o];
    }
}

// sigmoid(tanh(x)): tanh via fast exp+rcp (saturates correctly at +-inf),
// sigmoid via odd Taylor on [-1,1] (max abs err ~2e-4)
__device__ __forceinline__ float gsig(float x) {
    float E = __expf(2.0f * x);
    float t = 1.0f - 2.0f * __builtin_amdgcn_rcpf(E + 1.0f);   // tanh(x)
    float t2 = t * t;
    return fmaf(t, fmaf(t2, fmaf(t2, 0.0020833333f, -0.0208333333f), 0.25f), 0.5f);
}

// ---------------- pass 3: fused, 1 pixel/thread, fits 64 VGPR ----------------
__global__ __launch_bounds__(256, 8) void k_main(const float* __restrict__ x,
                                                 const float* __restrict__ params,
                                                 float* __restrict__ out) {
    int b = blockIdx.x >> 10;            // 1024 blocks per batch
    int j = blockIdx.x & 1023;
    int p = j * 256 + threadIdx.x;       // 1 pixel per thread
    const float* __restrict__ P = params + b * 816;   // block-uniform -> s_load
    const float* xb = x + (size_t)b * NC * HW + p;
    float* ob = out + (size_t)b * NC * HW + p;

    float v[NC];
    #pragma unroll
    for (int c = 0; c < NC; ++c)
        v[c] = xb[(size_t)c * HW];

    float acc[NC];
    #pragma unroll
    for (int q = 0; q < NC; ++q)
        acc[q] = P[800 + q];

    // two halves of 8 output channels keeps live set ~56 VGPRs
    #pragma unroll
    for (int oh = 0; oh < 2; ++oh) {
        float wh[8], gr[8];
        #pragma unroll
        for (int oo = 0; oo < 8; ++oo) {
            int o = oh * 8 + oo;
            wh[oo] = P[256 + o];
            gr[oo] = P[528 + o];
        }
        #pragma unroll
        for (int i = 0; i < NC; ++i) {
            float vi = v[i];
            #pragma unroll
            for (int oo = 0; oo < 8; ++oo) {
                int o = oh * 8 + oo;
                wh[oo] = fmaf(vi, P[i * NC + o], wh[oo]);
                gr[oo] = fmaf(vi, P[272 + i * NC + o], gr[oo]);
            }
        }
        #pragma unroll
        for (int oo = 0; oo < 8; ++oo) {
            int o = oh * 8 + oo;
            float s = gsig(wh[oo]) + gsig(gr[oo]);
            float u = fmaf(v[o], s, v[o]);     // v*(1+s1+s2)
            #pragma unroll
            for (int q = 0; q < NC; ++q)
                acc[q] = fmaf(u, P[544 + o * NC + q], acc[q]);
        }
    }

    #pragma unroll
    for (int q = 0; q < NC; ++q)
        ob[(size_t)q * HW] = acc[q];
}

extern "C" void kernel_launch(void* const* d_in, const int* in_sizes, int n_in,
                              void* d_out, int out_size, void* d_ws, size_t ws_size,
                              hipStream_t stream) {
    const float* x  = (const float*)d_in[0];
    const float* Wc = (const float*)d_in[1];
    const float* bc = (const float*)d_in[2];
    const float* W1 = (const float*)d_in[3];
    const float* b1 = (const float*)d_in[4];
    const float* W2 = (const float*)d_in[5];
    const float* b2 = (const float*)d_in[6];
    const float* W3 = (const float*)d_in[7];
    const float* b3 = (const float*)d_in[8];
    const float* W4 = (const float*)d_in[9];
    const float* b4 = (const float*)d_in[10];
    float* out = (float*)d_out;

    float* psum   = (float*)d_ws;                 // 128*16 floats
    float* pmax   = psum + NB * NC * NSEG;        // 128*16 floats
    float* params = pmax + NB * NC * NSEG;        // 8*816 floats

    k_reduce<<<NB * NC * NSEG, 256, 0, stream>>>(x, psum, pmax);
    k_params<<<NB, 256, 0, stream>>>(psum, pmax, Wc, bc, W1, b1, W2, b2,
                                     W3, b3, W4, b4, params);
    k_main<<<NB * 1024, 256, 0, stream>>>(x, params, out);
}

// Round 5
// 95.008 us; speedup vs baseline: 1.5573x; 1.5573x over previous
//
#include <hip/hip_runtime.h>
#include <hip/hip_bf16.h>
#include <cmath>

#define HW 262144          // 512*512
#define NC 16
#define NB 8
#define NSEG 16
#define SEGSZ (HW / NSEG)  // 16384
#define EPS 1e-5f

// ---------------- pass 1: per-(b,c,seg) partial sum & max ----------------
__global__ __launch_bounds__(256) void k_reduce(const float* __restrict__ x,
                                                float* __restrict__ psum,
                                                float* __restrict__ pmax) {
    int plane = blockIdx.x / NSEG;
    int seg   = blockIdx.x - plane * NSEG;
    const float4* p = reinterpret_cast<const float4*>(
        x + (size_t)plane * HW + (size_t)seg * SEGSZ);
    int t = threadIdx.x;
    float s = 0.0f, m = -INFINITY;
    #pragma unroll
    for (int it = 0; it < SEGSZ / (256 * 4); ++it) {
        float4 v = p[it * 256 + t];
        s += (v.x + v.y) + (v.z + v.w);
        m = fmaxf(m, fmaxf(fmaxf(v.x, v.y), fmaxf(v.z, v.w)));
    }
    #pragma unroll
    for (int off = 32; off > 0; off >>= 1) {
        s += __shfl_down(s, off, 64);
        m = fmaxf(m, __shfl_down(m, off, 64));
    }
    __shared__ float ls[4], lm[4];
    int wid = t >> 6, lane = t & 63;
    if (lane == 0) { ls[wid] = s; lm[wid] = m; }
    __syncthreads();
    if (t == 0) {
        psum[blockIdx.x] = (ls[0] + ls[1]) + (ls[2] + ls[3]);
        pmax[blockIdx.x] = fmaxf(fmaxf(lm[0], lm[1]), fmaxf(lm[2], lm[3]));
    }
}

// ---------------- pass 2: fold per-batch matrices ----------------
// params layout per batch (816 floats):
// [0:256)   A_T   (A[o][i] stored at i*16+o)
// [256:272) abias
// [272:528) G_T
// [528:544) gbias
// [544:800) W4_T  (W4[q][i] stored at i*16+q)
// [800:816) b4
__global__ __launch_bounds__(256) void k_params(
    const float* __restrict__ psum, const float* __restrict__ pmax,
    const float* __restrict__ Wc, const float* __restrict__ bc,
    const float* __restrict__ W1, const float* __restrict__ b1,
    const float* __restrict__ W2, const float* __restrict__ b2,
    const float* __restrict__ W3, const float* __restrict__ b3,
    const float* __restrict__ W4, const float* __restrict__ b4,
    float* __restrict__ params) {
    int b = blockIdx.x;
    int t = threadIdx.x;
    __shared__ float r2[NC], r4[NC], sWc[256], sW1[256], sW2[256], sW3[256];
    if (t < NC) {
        float s = 0.0f, m = -INFINITY;
        for (int k = 0; k < NSEG; ++k) {
            s += psum[(b * NC + t) * NSEG + k];
            m = fmaxf(m, pmax[(b * NC + t) * NSEG + k]);
        }
        r2[t] = 1.0f / (s * (1.0f / (float)HW) + EPS);
        r4[t] = 1.0f / (m + EPS);
    }
    sWc[t] = Wc[t]; sW1[t] = W1[t]; sW2[t] = W2[t]; sW3[t] = W3[t];
    __syncthreads();
    int o = t >> 4, i = t & 15;
    float accA = 0.0f, accG = 0.0f;
    #pragma unroll
    for (int c = 0; c < NC; ++c) {
        accA += sW2[o * NC + c] * r2[c] * sWc[c * NC + i];
        accG += sW3[o * NC + c] * r4[c] * sW1[c * NC + i];
    }
    float* P = params + b * 816;
    P[i * NC + o]       = accA;
    P[272 + i * NC + o] = accG;
    P[544 + i * NC + o] = W4[o * NC + i];
    if (i == 0) {
        float ba = 0.0f, bg = 0.0f;
        #pragma unroll
        for (int c = 0; c < NC; ++c) {
            ba += sW2[o * NC + c] * r2[c] * bc[c];
            bg += sW3[o * NC + c] * r4[c] * b1[c];
        }
        P[256 + o] = ba + b2[o];
        P[528 + o] = bg + b3[o];
        P[800 + o] = b4[o];
    }
}

// sigmoid(tanh(x)): tanh via fast exp+rcp (saturates correctly at +-inf),
// sigmoid via odd Taylor on [-1,1] (max abs err ~2e-4)
__device__ __forceinline__ float gsig(float x) {
    float E = __expf(2.0f * x);
    float t = 1.0f - 2.0f * __builtin_amdgcn_rcpf(E + 1.0f);   // tanh(x)
    float t2 = t * t;
    return fmaf(t, fmaf(t2, fmaf(t2, 0.0020833333f, -0.0208333333f), 0.25f), 0.5f);
}

// ---------------- pass 3: fused, 2 px/thread, RA pinned to 4 waves/EU ----------------
// amdgpu_waves_per_eu(4,4): stop the occupancy-driven register squeeze.
// Budget = 512/4 = 128 VGPR; live set v(32)+acc(32)+wh/gr(32)+temps ~ 112.
__global__ __launch_bounds__(256) __attribute__((amdgpu_waves_per_eu(4, 4)))
void k_main(const float* __restrict__ x,
            const float* __restrict__ params,
            float* __restrict__ out) {
    int b = blockIdx.x >> 9;            // 512 blocks per batch
    int j = blockIdx.x & 511;
    int p = j * 512 + threadIdx.x * 2;  // 2 pixels per thread
    const float* __restrict__ P = params + b * 816;   // block-uniform -> s_load
    const float* xb = x + (size_t)b * NC * HW + p;
    float* ob = out + (size_t)b * NC * HW + p;

    float2 v[NC];
    #pragma unroll
    for (int c = 0; c < NC; ++c)
        v[c] = *reinterpret_cast<const float2*>(xb + (size_t)c * HW);

    float2 acc[NC];

    // two halves of 8 output channels
    #pragma unroll
    for (int oh = 0; oh < 2; ++oh) {
        float whx[8], why[8], grx[8], gry[8];
        #pragma unroll
        for (int oo = 0; oo < 8; ++oo) {
            int o = oh * 8 + oo;
            whx[oo] = P[256 + o]; why[oo] = whx[oo];
            grx[oo] = P[528 + o]; gry[oo] = grx[oo];
        }
        #pragma unroll
        for (int i = 0; i < NC; ++i) {
            float vx = v[i].x, vy = v[i].y;
            #pragma unroll
            for (int oo = 0; oo < 8; ++oo) {
                int o = oh * 8 + oo;
                float a = P[i * NC + o];
                float g = P[272 + i * NC + o];
                whx[oo] = fmaf(vx, a, whx[oo]); why[oo] = fmaf(vy, a, why[oo]);
                grx[oo] = fmaf(vx, g, grx[oo]); gry[oo] = fmaf(vy, g, gry[oo]);
            }
        }
        #pragma unroll
        for (int oo = 0; oo < 8; ++oo) {
            int o = oh * 8 + oo;
            float sx = gsig(whx[oo]) + gsig(grx[oo]);
            float sy = gsig(why[oo]) + gsig(gry[oo]);
            float ux = fmaf(v[o].x, sx, v[o].x);   // v*(1+s1+s2)
            float uy = fmaf(v[o].y, sy, v[o].y);
            #pragma unroll
            for (int q = 0; q < NC; ++q) {
                float wv = P[544 + o * NC + q];    // W4[q][o]
                if (oh == 0 && oo == 0) {          // fold bias into first scatter
                    float bb = P[800 + q];
                    acc[q].x = fmaf(ux, wv, bb);
                    acc[q].y = fmaf(uy, wv, bb);
                } else {
                    acc[q].x = fmaf(ux, wv, acc[q].x);
                    acc[q].y = fmaf(uy, wv, acc[q].y);
                }
            }
        }
    }

    #pragma unroll
    for (int q = 0; q < NC; ++q)
        *reinterpret_cast<float2*>(ob + (size_t)q * HW) = acc[q];
}

extern "C" void kernel_launch(void* const* d_in, const int* in_sizes, int n_in,
                              void* d_out, int out_size, void* d_ws, size_t ws_size,
                              hipStream_t stream) {
    const float* x  = (const float*)d_in[0];
    const float* Wc = (const float*)d_in[1];
    const float* bc = (const float*)d_in[2];
    const float* W1 = (const float*)d_in[3];
    const float* b1 = (const float*)d_in[4];
    const float* W2 = (const float*)d_in[5];
    const float* b2 = (const float*)d_in[6];
    const float* W3 = (const float*)d_in[7];
    const float* b3 = (const float*)d_in[8];
    const float* W4 = (const float*)d_in[9];
    const float* b4 = (const float*)d_in[10];
    float* out = (float*)d_out;

    float* psum   = (float*)d_ws;                 // 128*16 floats
    float* pmax   = psum + NB * NC * NSEG;        // 128*16 floats
    float* params = pmax + NB * NC * NSEG;        // 8*816 floats

    k_reduce<<<NB * NC * NSEG, 256, 0, stream>>>(x, psum, pmax);
    k_params<<<NB, 256, 0, stream>>>(psum, pmax, Wc, bc, W1, b1, W2, b2,
                                     W3, b3, W4, b4, params);
    k_main<<<NB * 512, 256, 0, stream>>>(x, params, out);
}

// Round 6
// 91.789 us; speedup vs baseline: 1.6119x; 1.0351x over previous
//
#include <hip/hip_runtime.h>
#include <hip/hip_bf16.h>
#include <cmath>

#define HW 262144          // 512*512
#define NC 16
#define NB 8
#define NSEG 16
#define SEGSZ (HW / NSEG)  // 16384
#define EPS 1e-5f

// ---------------- pass 1: per-(b,c,seg) partial sum & max ----------------
__global__ __launch_bounds__(256) void k_reduce(const float* __restrict__ x,
                                                float* __restrict__ psum,
                                                float* __restrict__ pmax) {
    int plane = blockIdx.x / NSEG;
    int seg   = blockIdx.x - plane * NSEG;
    const float4* p = reinterpret_cast<const float4*>(
        x + (size_t)plane * HW + (size_t)seg * SEGSZ);
    int t = threadIdx.x;
    float s = 0.0f, m = -INFINITY;
    #pragma unroll
    for (int it = 0; it < SEGSZ / (256 * 4); ++it) {
        float4 v = p[it * 256 + t];
        s += (v.x + v.y) + (v.z + v.w);
        m = fmaxf(m, fmaxf(fmaxf(v.x, v.y), fmaxf(v.z, v.w)));
    }
    #pragma unroll
    for (int off = 32; off > 0; off >>= 1) {
        s += __shfl_down(s, off, 64);
        m = fmaxf(m, __shfl_down(m, off, 64));
    }
    __shared__ float ls[4], lm[4];
    int wid = t >> 6, lane = t & 63;
    if (lane == 0) { ls[wid] = s; lm[wid] = m; }
    __syncthreads();
    if (t == 0) {
        psum[blockIdx.x] = (ls[0] + ls[1]) + (ls[2] + ls[3]);
        pmax[blockIdx.x] = fmaxf(fmaxf(lm[0], lm[1]), fmaxf(lm[2], lm[3]));
    }
}

// ---------------- pass 2: fold per-batch matrices ----------------
// params layout per batch (816 floats):
// [0:256)   A_T   (A[o][i] stored at i*16+o  -> column o contiguous-ish for o-outer)
// [256:272) abias
// [272:528) G_T
// [528:544) gbias
// [544:800) W4 row-major (W4[q][o] at 544 + q*16 + o)
// [800:816) b4
__global__ __launch_bounds__(256) void k_params(
    const float* __restrict__ psum, const float* __restrict__ pmax,
    const float* __restrict__ Wc, const float* __restrict__ bc,
    const float* __restrict__ W1, const float* __restrict__ b1,
    const float* __restrict__ W2, const float* __restrict__ b2,
    const float* __restrict__ W3, const float* __restrict__ b3,
    const float* __restrict__ W4, const float* __restrict__ b4,
    float* __restrict__ params) {
    int b = blockIdx.x;
    int t = threadIdx.x;
    __shared__ float r2[NC], r4[NC], sWc[256], sW1[256], sW2[256], sW3[256];
    if (t < NC) {
        float s = 0.0f, m = -INFINITY;
        for (int k = 0; k < NSEG; ++k) {
            s += psum[(b * NC + t) * NSEG + k];
            m = fmaxf(m, pmax[(b * NC + t) * NSEG + k]);
        }
        r2[t] = 1.0f / (s * (1.0f / (float)HW) + EPS);
        r4[t] = 1.0f / (m + EPS);
    }
    sWc[t] = Wc[t]; sW1[t] = W1[t]; sW2[t] = W2[t]; sW3[t] = W3[t];
    __syncthreads();
    int o = t >> 4, i = t & 15;
    float accA = 0.0f, accG = 0.0f;
    #pragma unroll
    for (int c = 0; c < NC; ++c) {
        accA += sW2[o * NC + c] * r2[c] * sWc[c * NC + i];
        accG += sW3[o * NC + c] * r4[c] * sW1[c * NC + i];
    }
    float* P = params + b * 816;
    P[i * NC + o]       = accA;
    P[272 + i * NC + o] = accG;
    P[544 + t]          = W4[t];          // row-major: W4[q][o] at q*16+o
    if (i == 0) {
        float ba = 0.0f, bg = 0.0f;
        #pragma unroll
        for (int c = 0; c < NC; ++c) {
            ba += sW2[o * NC + c] * r2[c] * bc[c];
            bg += sW3[o * NC + c] * r4[c] * b1[c];
        }
        P[256 + o] = ba + b2[o];
        P[528 + o] = bg + b3[o];
        P[800 + o] = b4[o];
    }
}

// sigmoid(tanh(x)): tanh via fast exp+rcp (saturates correctly at +-inf),
// sigmoid via odd Taylor on [-1,1] (max abs err ~2e-4)
__device__ __forceinline__ float gsig(float x) {
    float E = __expf(2.0f * x);
    float t = 1.0f - 2.0f * __builtin_amdgcn_rcpf(E + 1.0f);   // tanh(x)
    float t2 = t * t;
    return fmaf(t, fmaf(t2, fmaf(t2, 0.0020833333f, -0.0208333333f), 0.25f), 0.5f);
}

// ---------------- pass 3: fused, 1 px/thread, two-phase, live set < 64 VGPR ----
// Phase B: u[o] = v[o]*(1+gsig(wh_o)+gsig(gr_o)) — v[16]+u[<=16] live.
// Phase C: out[q] = b4[q] + sum_o W4[q][o]*u[o]  — v dead, u[16]+4 chains live.
// Peak ~45 VGPR: under the 64-reg tier the RA always targets, so no remat.
__global__ __launch_bounds__(256) void k_main(const float* __restrict__ x,
                                              const float* __restrict__ params,
                                              float* __restrict__ out) {
    int b = blockIdx.x >> 10;            // 1024 blocks per batch
    int j = blockIdx.x & 1023;
    int p = j * 256 + threadIdx.x;       // 1 pixel per thread
    const float* __restrict__ P = params + b * 816;   // block-uniform -> s_load
    const float* xb = x + (size_t)b * NC * HW + p;
    float* ob = out + (size_t)b * NC * HW + p;

    float v[NC];
    #pragma unroll
    for (int c = 0; c < NC; ++c)
        v[c] = xb[(size_t)c * HW];

    float u[NC];
    #pragma unroll
    for (int o = 0; o < NC; ++o) {
        float wh = P[256 + o];
        float gr = P[528 + o];
        #pragma unroll
        for (int i = 0; i < NC; ++i) {
            float vi = v[i];
            wh = fmaf(vi, P[i * NC + o], wh);
            gr = fmaf(vi, P[272 + i * NC + o], gr);
        }
        float s = gsig(wh) + gsig(gr);
        u[o] = fmaf(v[o], s, v[o]);        // v*(1+s1+s2)
    }

    // q-major output matvec, 4 chains at a time for ILP, store as ready
    #pragma unroll
    for (int q4 = 0; q4 < NC; q4 += 4) {
        float a0 = P[800 + q4 + 0];
        float a1 = P[800 + q4 + 1];
        float a2 = P[800 + q4 + 2];
        float a3 = P[800 + q4 + 3];
        #pragma unroll
        for (int o = 0; o < NC; ++o) {
            float uo = u[o];
            a0 = fmaf(uo, P[544 + (q4 + 0) * NC + o], a0);
            a1 = fmaf(uo, P[544 + (q4 + 1) * NC + o], a1);
            a2 = fmaf(uo, P[544 + (q4 + 2) * NC + o], a2);
            a3 = fmaf(uo, P[544 + (q4 + 3) * NC + o], a3);
        }
        ob[(size_t)(q4 + 0) * HW] = a0;
        ob[(size_t)(q4 + 1) * HW] = a1;
        ob[(size_t)(q4 + 2) * HW] = a2;
        ob[(size_t)(q4 + 3) * HW] = a3;
    }
}

extern "C" void kernel_launch(void* const* d_in, const int* in_sizes, int n_in,
                              void* d_out, int out_size, void* d_ws, size_t ws_size,
                              hipStream_t stream) {
    const float* x  = (const float*)d_in[0];
    const float* Wc = (const float*)d_in[1];
    const float* bc = (const float*)d_in[2];
    const float* W1 = (const float*)d_in[3];
    const float* b1 = (const float*)d_in[4];
    const float* W2 = (const float*)d_in[5];
    const float* b2 = (const float*)d_in[6];
    const float* W3 = (const float*)d_in[7];
    const float* b3 = (const float*)d_in[8];
    const float* W4 = (const float*)d_in[9];
    const float* b4 = (const float*)d_in[10];
    float* out = (float*)d_out;

    float* psum   = (float*)d_ws;                 // 128*16 floats
    float* pmax   = psum + NB * NC * NSEG;        // 128*16 floats
    float* params = pmax + NB * NC * NSEG;        // 8*816 floats

    k_reduce<<<NB * NC * NSEG, 256, 0, stream>>>(x, psum, pmax);
    k_params<<<NB, 256, 0, stream>>>(psum, pmax, Wc, bc, W1, b1, W2, b2,
                                     W3, b3, W4, b4, params);
    k_main<<<NB * 1024, 256, 0, stream>>>(x, params, out);
}

// Round 7
// 85.525 us; speedup vs baseline: 1.7299x; 1.0732x over previous
//
#include <hip/hip_runtime.h>
#include <hip/hip_bf16.h>
#include <cmath>

#define HW 262144          // 512*512
#define NC 16
#define NB 8
#define NSEG 16
#define SEGSZ (HW / NSEG)  // 16384
#define EPS 1e-5f

typedef float f32x4 __attribute__((ext_vector_type(4)));
typedef short bf16x8 __attribute__((ext_vector_type(8)));

// ---------------- pass 1: per-(b,c,seg) partial sum & max ----------------
__global__ __launch_bounds__(256) void k_reduce(const float* __restrict__ x,
                                                float* __restrict__ psum,
                                                float* __restrict__ pmax) {
    int plane = blockIdx.x / NSEG;
    int seg   = blockIdx.x - plane * NSEG;
    const float4* p = reinterpret_cast<const float4*>(
        x + (size_t)plane * HW + (size_t)seg * SEGSZ);
    int t = threadIdx.x;
    float s = 0.0f, m = -INFINITY;
    #pragma unroll
    for (int it = 0; it < SEGSZ / (256 * 4); ++it) {
        float4 v = p[it * 256 + t];
        s += (v.x + v.y) + (v.z + v.w);
        m = fmaxf(m, fmaxf(fmaxf(v.x, v.y), fmaxf(v.z, v.w)));
    }
    #pragma unroll
    for (int off = 32; off > 0; off >>= 1) {
        s += __shfl_down(s, off, 64);
        m = fmaxf(m, __shfl_down(m, off, 64));
    }
    __shared__ float ls[4], lm[4];
    int wid = t >> 6, lane = t & 63;
    if (lane == 0) { ls[wid] = s; lm[wid] = m; }
    __syncthreads();
    if (t == 0) {
        psum[blockIdx.x] = (ls[0] + ls[1]) + (ls[2] + ls[3]);
        pmax[blockIdx.x] = fmaxf(fmaxf(lm[0], lm[1]), fmaxf(lm[2], lm[3]));
    }
}

// ---------------- pass 2: fold per-batch matrices ----------------
// params layout per batch (816 floats), ALL row-major [o][i] at o*16+i:
// [0:256)   A  = W2*diag(1/(mean+eps))*Wc
// [256:512) G  = W3*diag(1/(max+eps))*W1
// [512:768) W4
// [768:784) abias = W2*diag(r2)*bc + b2
// [784:800) gbias = W3*diag(r4)*b1 + b3
// [800:816) b4
__global__ __launch_bounds__(256) void k_params(
    const float* __restrict__ psum, const float* __restrict__ pmax,
    const float* __restrict__ Wc, const float* __restrict__ bc,
    const float* __restrict__ W1, const float* __restrict__ b1,
    const float* __restrict__ W2, const float* __restrict__ b2,
    const float* __restrict__ W3, const float* __restrict__ b3,
    const float* __restrict__ W4, const float* __restrict__ b4,
    float* __restrict__ params) {
    int b = blockIdx.x;
    int t = threadIdx.x;
    __shared__ float r2[NC], r4[NC], sWc[256], sW1[256], sW2[256], sW3[256];
    if (t < NC) {
        float s = 0.0f, m = -INFINITY;
        for (int k = 0; k < NSEG; ++k) {
            s += psum[(b * NC + t) * NSEG + k];
            m = fmaxf(m, pmax[(b * NC + t) * NSEG + k]);
        }
        r2[t] = 1.0f / (s * (1.0f / (float)HW) + EPS);
        r4[t] = 1.0f / (m + EPS);
    }
    sWc[t] = Wc[t]; sW1[t] = W1[t]; sW2[t] = W2[t]; sW3[t] = W3[t];
    __syncthreads();
    int o = t >> 4, i = t & 15;
    float accA = 0.0f, accG = 0.0f;
    #pragma unroll
    for (int c = 0; c < NC; ++c) {
        accA += sW2[o * NC + c] * r2[c] * sWc[c * NC + i];
        accG += sW3[o * NC + c] * r4[c] * sW1[c * NC + i];
    }
    float* P = params + b * 816;
    P[t]       = accA;          // A[o][i]
    P[256 + t] = accG;          // G[o][i]
    P[512 + t] = W4[t];         // W4[o][i] (already row-major)
    if (i == 0) {
        float ba = 0.0f, bg = 0.0f;
        #pragma unroll
        for (int c = 0; c < NC; ++c) {
            ba += sW2[o * NC + c] * r2[c] * bc[c];
            bg += sW3[o * NC + c] * r4[c] * b1[c];
        }
        P[768 + o] = ba + b2[o];
        P[784 + o] = bg + b3[o];
        P[800 + o] = b4[o];
    }
}

// sigmoid(tanh(x)): tanh via fast exp+rcp (saturates correctly at +-inf),
// sigmoid via odd Taylor on [-1,1] (max abs err ~2e-4)
__device__ __forceinline__ float gsig(float x) {
    float E = __expf(2.0f * x);
    float t = 1.0f - 2.0f * __builtin_amdgcn_rcpf(E + 1.0f);   // tanh(x)
    float t2 = t * t;
    return fmaf(t, fmaf(t2, fmaf(t2, 0.0020833333f, -0.0208333333f), 0.25f), 0.5f);
}

static __device__ __forceinline__ bf16x8 mk8(unsigned a, unsigned b,
                                             unsigned c, unsigned d) {
    union { unsigned u[4]; bf16x8 v; } r;
    r.u[0] = a; r.u[1] = b; r.u[2] = c; r.u[3] = d;
    return r.v;
}

// pack bf16-truncations of (x0,x1) -> one u32 (lo=bf16(x0), hi=bf16(x1))
static __device__ __forceinline__ unsigned pkhi(float x0, float x1) {
    return (__float_as_uint(x0) >> 16) | (__float_as_uint(x1) & 0xFFFF0000u);
}
// f32 value of the bf16-truncation
static __device__ __forceinline__ float trunc_bf(float x) {
    return __uint_as_float(__float_as_uint(x) & 0xFFFF0000u);
}

// ---------------- pass 3: MFMA tiles (16 px x 16 ch per mfma) ----------------
// Per wave: 16 tiles of 16 pixels (256 px contiguous).
// Fragment maps (mfma_f32_16x16x32_bf16):
//   A[m][k]: m = lane%16, k = (lane/16)*4 + i  (elems 0-3 -> K-half-1, 4-7 -> K-half-2)
//   B[k][n]: n = lane%16, k = (lane/16)*4 + i  (same half split)
//   C/D    : col(n) = lane&15, row(m) = (lane>>4)*4 + reg   [m89-verified]
// Split-bf16: A32=[Ah|Al], B1=[vh;vl], B2=[vl;vh]:
//   A32*B1 + A32*B2 = (Ah+Al)(vh+vl)  — full product, rel err ~2^-17,
//   immune to K-half-convention (all 4 cross terms always covered).
__global__ __launch_bounds__(256) void k_main(const float* __restrict__ x,
                                              const float* __restrict__ params,
                                              float* __restrict__ out) {
    int b   = blockIdx.x >> 8;                    // 256 blocks per batch
    int wib = ((blockIdx.x & 255) << 2) + (threadIdx.x >> 6);  // wave in batch [0,1024)
    int lane = threadIdx.x & 63;
    int m  = lane & 15;                           // row for A-frag / pixel for B,D
    int kg = lane >> 4;                           // k-group / row-group

    const float* Pb = params + b * 816;

    // ---- weight fragments (once) ----
    f32x4 wa = *reinterpret_cast<const f32x4*>(Pb + m * 16 + kg * 4);
    f32x4 wg = *reinterpret_cast<const f32x4*>(Pb + 256 + m * 16 + kg * 4);
    f32x4 w4 = *reinterpret_cast<const f32x4*>(Pb + 512 + m * 16 + kg * 4);

    unsigned ah01 = pkhi(wa[0], wa[1]), ah23 = pkhi(wa[2], wa[3]);
    unsigned al01 = pkhi(wa[0] - trunc_bf(wa[0]), wa[1] - trunc_bf(wa[1]));
    unsigned al23 = pkhi(wa[2] - trunc_bf(wa[2]), wa[3] - trunc_bf(wa[3]));
    bf16x8 Af = mk8(ah01, ah23, al01, al23);      // [Ah | Al]

    unsigned g01 = pkhi(wg[0], wg[1]), g23 = pkhi(wg[2], wg[3]);
    bf16x8 Gf = mk8(g01, g23, g01, g23);          // [G | G]

    unsigned wh01 = pkhi(w4[0], w4[1]), wh23 = pkhi(w4[2], w4[3]);
    unsigned wl01 = pkhi(w4[0] - trunc_bf(w4[0]), w4[1] - trunc_bf(w4[1]));
    unsigned wl23 = pkhi(w4[2] - trunc_bf(w4[2]), w4[3] - trunc_bf(w4[3]));
    bf16x8 Wf = mk8(wh01, wh23, wl01, wl23);      // [W4h | W4l]

    f32x4 biasA = *reinterpret_cast<const f32x4*>(Pb + 768 + kg * 4);
    f32x4 biasG = *reinterpret_cast<const f32x4*>(Pb + 784 + kg * 4);
    f32x4 biasW = *reinterpret_cast<const f32x4*>(Pb + 800 + kg * 4);

    // ---- per-lane plane offsets (elements): channel kg*4+j, pixel base+m ----
    const float* xb = x   + (size_t)b * NC * HW;
    float*       ob = out + (size_t)b * NC * HW;
    unsigned px0 = (unsigned)wib * 256 + (unsigned)m;
    unsigned vo0 = (unsigned)(kg * 4 + 0) * HW + px0;
    unsigned vo1 = (unsigned)(kg * 4 + 1) * HW + px0;
    unsigned vo2 = (unsigned)(kg * 4 + 2) * HW + px0;
    unsigned vo3 = (unsigned)(kg * 4 + 3) * HW + px0;

    #pragma unroll
    for (int t = 0; t < 16; ++t) {
        float x0 = xb[vo0 + t * 16];
        float x1 = xb[vo1 + t * 16];
        float x2 = xb[vo2 + t * 16];
        float x3 = xb[vo3 + t * 16];

        // split x into bf16 hi+lo packed fragments
        unsigned vh01 = pkhi(x0, x1), vh23 = pkhi(x2, x3);
        unsigned vl01 = pkhi(x0 - trunc_bf(x0), x1 - trunc_bf(x1));
        unsigned vl23 = pkhi(x2 - trunc_bf(x2), x3 - trunc_bf(x3));
        bf16x8 B1 = mk8(vh01, vh23, vl01, vl23);  // [vh ; vl]
        bf16x8 B2 = mk8(vl01, vl23, vh01, vh23);  // [vl ; vh]

        // wh = A*v + abias (split product), gr = G*v + gbias
        f32x4 wh = __builtin_amdgcn_mfma_f32_16x16x32_bf16(Af, B1, biasA, 0, 0, 0);
        wh = __builtin_amdgcn_mfma_f32_16x16x32_bf16(Af, B2, wh, 0, 0, 0);
        f32x4 gr = __builtin_amdgcn_mfma_f32_16x16x32_bf16(Gf, B1, biasG, 0, 0, 0);

        // u = x * (1 + gsig(wh) + gsig(gr))   (channel m-row == load channel)
        float s0 = gsig(wh[0]) + gsig(gr[0]);
        float s1 = gsig(wh[1]) + gsig(gr[1]);
        float s2 = gsig(wh[2]) + gsig(gr[2]);
        float s3 = gsig(wh[3]) + gsig(gr[3]);
        float u0 = fmaf(x0, s0, x0);
        float u1 = fmaf(x1, s1, x1);
        float u2 = fmaf(x2, s2, x2);
        float u3 = fmaf(x3, s3, x3);

        // split u, final matmul: out = W4*u + b4 (split product)
        unsigned uh01 = pkhi(u0, u1), uh23 = pkhi(u2, u3);
        unsigned ul01 = pkhi(u0 - trunc_bf(u0), u1 - trunc_bf(u1));
        unsigned ul23 = pkhi(u2 - trunc_bf(u2), u3 - trunc_bf(u3));
        bf16x8 U1 = mk8(uh01, uh23, ul01, ul23);
        bf16x8 U2 = mk8(ul01, ul23, uh01, uh23);

        f32x4 o4 = __builtin_amdgcn_mfma_f32_16x16x32_bf16(Wf, U1, biasW, 0, 0, 0);
        o4 = __builtin_amdgcn_mfma_f32_16x16x32_bf16(Wf, U2, o4, 0, 0, 0);

        ob[vo0 + t * 16] = o4[0];
        ob[vo1 + t * 16] = o4[1];
        ob[vo2 + t * 16] = o4[2];
        ob[vo3 + t * 16] = o4[3];
    }
}

extern "C" void kernel_launch(void* const* d_in, const int* in_sizes, int n_in,
                              void* d_out, int out_size, void* d_ws, size_t ws_size,
                              hipStream_t stream) {
    const float* x  = (const float*)d_in[0];
    const float* Wc = (const float*)d_in[1];
    const float* bc = (const float*)d_in[2];
    const float* W1 = (const float*)d_in[3];
    const float* b1 = (const float*)d_in[4];
    const float* W2 = (const float*)d_in[5];
    const float* b2 = (const float*)d_in[6];
    const float* W3 = (const float*)d_in[7];
    const float* b3 = (const float*)d_in[8];
    const float* W4 = (const float*)d_in[9];
    const float* b4 = (const float*)d_in[10];
    float* out = (float*)d_out;

    float* psum   = (float*)d_ws;                 // 128*16 floats
    float* pmax   = psum + NB * NC * NSEG;        // 128*16 floats
    float* params = pmax + NB * NC * NSEG;        // 8*816 floats

    k_reduce<<<NB * NC * NSEG, 256, 0, stream>>>(x, psum, pmax);
    k_params<<<NB, 256, 0, stream>>>(psum, pmax, Wc, bc, W1, b1, W2, b2,
                                     W3, b3, W4, b4, params);
    k_main<<<NB * 256, 256, 0, stream>>>(x, params, out);
}

// Round 9
// 70.491 us; speedup vs baseline: 2.0989x; 1.2133x over previous
//
#include <hip/hip_runtime.h>
#include <hip/hip_bf16.h>
#include <cmath>

#define HW 262144          // 512*512
#define NC 16
#define NB 8
#define NSEG 16
#define SEGSZ (HW / NSEG)  // 16384
#define EPS 1e-5f

typedef float f32x4 __attribute__((ext_vector_type(4)));
typedef float f32x2 __attribute__((ext_vector_type(2)));
typedef short bf16x8 __attribute__((ext_vector_type(8)));

// ---------------- pass 1: per-(b,c,seg) partial sum & max ----------------
__global__ __launch_bounds__(256) void k_reduce(const float* __restrict__ x,
                                                float* __restrict__ psum,
                                                float* __restrict__ pmax) {
    int plane = blockIdx.x / NSEG;
    int seg   = blockIdx.x - plane * NSEG;
    const float4* p = reinterpret_cast<const float4*>(
        x + (size_t)plane * HW + (size_t)seg * SEGSZ);
    int t = threadIdx.x;
    float s = 0.0f, m = -INFINITY;
    #pragma unroll
    for (int it = 0; it < SEGSZ / (256 * 4); ++it) {
        float4 v = p[it * 256 + t];
        s += (v.x + v.y) + (v.z + v.w);
        m = fmaxf(m, fmaxf(fmaxf(v.x, v.y), fmaxf(v.z, v.w)));
    }
    #pragma unroll
    for (int off = 32; off > 0; off >>= 1) {
        s += __shfl_down(s, off, 64);
        m = fmaxf(m, __shfl_down(m, off, 64));
    }
    __shared__ float ls[4], lm[4];
    int wid = t >> 6, lane = t & 63;
    if (lane == 0) { ls[wid] = s; lm[wid] = m; }
    __syncthreads();
    if (t == 0) {
        psum[blockIdx.x] = (ls[0] + ls[1]) + (ls[2] + ls[3]);
        pmax[blockIdx.x] = fmaxf(fmaxf(lm[0], lm[1]), fmaxf(lm[2], lm[3]));
    }
}

// ---------------- pass 2: fold per-batch matrices ----------------
// params layout per batch (816 floats), ALL row-major [o][i] at o*16+i:
// [0:256)   A  = W2*diag(1/(mean+eps))*Wc
// [256:512) G  = W3*diag(1/(max+eps))*W1
// [512:768) W4
// [768:784) abias   [784:800) gbias   [800:816) b4
__global__ __launch_bounds__(256) void k_params(
    const float* __restrict__ psum, const float* __restrict__ pmax,
    const float* __restrict__ Wc, const float* __restrict__ bc,
    const float* __restrict__ W1, const float* __restrict__ b1,
    const float* __restrict__ W2, const float* __restrict__ b2,
    const float* __restrict__ W3, const float* __restrict__ b3,
    const float* __restrict__ W4, const float* __restrict__ b4,
    float* __restrict__ params) {
    int b = blockIdx.x;
    int t = threadIdx.x;
    __shared__ float r2[NC], r4[NC], sWc[256], sW1[256], sW2[256], sW3[256];
    if (t < NC) {
        float s = 0.0f, m = -INFINITY;
        for (int k = 0; k < NSEG; ++k) {
            s += psum[(b * NC + t) * NSEG + k];
            m = fmaxf(m, pmax[(b * NC + t) * NSEG + k]);
        }
        r2[t] = 1.0f / (s * (1.0f / (float)HW) + EPS);
        r4[t] = 1.0f / (m + EPS);
    }
    sWc[t] = Wc[t]; sW1[t] = W1[t]; sW2[t] = W2[t]; sW3[t] = W3[t];
    __syncthreads();
    int o = t >> 4, i = t & 15;
    float accA = 0.0f, accG = 0.0f;
    #pragma unroll
    for (int c = 0; c < NC; ++c) {
        accA += sW2[o * NC + c] * r2[c] * sWc[c * NC + i];
        accG += sW3[o * NC + c] * r4[c] * sW1[c * NC + i];
    }
    float* P = params + b * 816;
    P[t]       = accA;          // A[o][i]
    P[256 + t] = accG;          // G[o][i]
    P[512 + t] = W4[t];         // W4[o][i]
    if (i == 0) {
        float ba = 0.0f, bg = 0.0f;
        #pragma unroll
        for (int c = 0; c < NC; ++c) {
            ba += sW2[o * NC + c] * r2[c] * bc[c];
            bg += sW3[o * NC + c] * r4[c] * b1[c];
        }
        P[768 + o] = ba + b2[o];
        P[784 + o] = bg + b3[o];
        P[800 + o] = b4[o];
    }
}

// sigmoid(tanh(x)): tanh via fast exp+rcp, sigmoid via odd Taylor on [-1,1]
__device__ __forceinline__ float gsig(float x) {
    float E = __expf(2.0f * x);
    float t = 1.0f - 2.0f * __builtin_amdgcn_rcpf(E + 1.0f);   // tanh(x)
    float t2 = t * t;
    return fmaf(t, fmaf(t2, fmaf(t2, 0.0020833333f, -0.0208333333f), 0.25f), 0.5f);
}

static __device__ __forceinline__ bf16x8 mk8(unsigned a, unsigned b,
                                             unsigned c, unsigned d) {
    union { unsigned u[4]; bf16x8 v; } r;
    r.u[0] = a; r.u[1] = b; r.u[2] = c; r.u[3] = d;
    return r.v;
}
static __device__ __forceinline__ unsigned pkhi(float x0, float x1) {
    return (__float_as_uint(x0) >> 16) | (__float_as_uint(x1) & 0xFFFF0000u);
}
static __device__ __forceinline__ float trunc_bf(float x) {
    return __uint_as_float(__float_as_uint(x) & 0xFFFF0000u);
}

// one 16ch x 16px MFMA tile: x0..x3 = this lane's 4 channels at its column
static __device__ __forceinline__ f32x4 tile16(float x0, float x1, float x2, float x3,
                                               bf16x8 Af, bf16x8 Gf, bf16x8 Wf,
                                               f32x4 biasA, f32x4 biasG, f32x4 biasW) {
    unsigned vh01 = pkhi(x0, x1), vh23 = pkhi(x2, x3);
    unsigned vl01 = pkhi(x0 - trunc_bf(x0), x1 - trunc_bf(x1));
    unsigned vl23 = pkhi(x2 - trunc_bf(x2), x3 - trunc_bf(x3));
    bf16x8 B1 = mk8(vh01, vh23, vl01, vl23);   // [vh ; vl]
    bf16x8 B2 = mk8(vl01, vl23, vh01, vh23);   // [vl ; vh]
    f32x4 wh = __builtin_amdgcn_mfma_f32_16x16x32_bf16(Af, B1, biasA, 0, 0, 0);
    wh = __builtin_amdgcn_mfma_f32_16x16x32_bf16(Af, B2, wh, 0, 0, 0);
    f32x4 gr = __builtin_amdgcn_mfma_f32_16x16x32_bf16(Gf, B1, biasG, 0, 0, 0);
    float u0 = fmaf(x0, gsig(wh[0]) + gsig(gr[0]), x0);
    float u1 = fmaf(x1, gsig(wh[1]) + gsig(gr[1]), x1);
    float u2 = fmaf(x2, gsig(wh[2]) + gsig(gr[2]), x2);
    float u3 = fmaf(x3, gsig(wh[3]) + gsig(gr[3]), x3);
    unsigned uh01 = pkhi(u0, u1), uh23 = pkhi(u2, u3);
    unsigned ul01 = pkhi(u0 - trunc_bf(u0), u1 - trunc_bf(u1));
    unsigned ul23 = pkhi(u2 - trunc_bf(u2), u3 - trunc_bf(u3));
    f32x4 o = __builtin_amdgcn_mfma_f32_16x16x32_bf16(Wf, mk8(uh01, uh23, ul01, ul23), biasW, 0, 0, 0);
    o = __builtin_amdgcn_mfma_f32_16x16x32_bf16(Wf, mk8(ul01, ul23, uh01, uh23), o, 0, 0, 0);
    return o;
}

// ---------------- pass 3: MFMA, f32x2 lanes -> 2 interleaved tiles --------
// Tile j column n <-> pixel 2n+j: lane m's f32x2 components are (col m, tile 0/1).
// Loads/stores: 16 lanes x 8B = 128B full lines per channel segment.
__global__ __launch_bounds__(256) void k_main(const float* __restrict__ x,
                                              const float* __restrict__ params,
                                              float* __restrict__ out) {
    int b    = blockIdx.x >> 8;                                // 256 blocks/batch
    int wib  = ((blockIdx.x & 255) << 2) + (threadIdx.x >> 6); // wave in batch
    int lane = threadIdx.x & 63;
    int m  = lane & 15;
    int kg = lane >> 4;

    const float* Pb = params + b * 816;

    f32x4 wa = *reinterpret_cast<const f32x4*>(Pb + m * 16 + kg * 4);
    f32x4 wg = *reinterpret_cast<const f32x4*>(Pb + 256 + m * 16 + kg * 4);
    f32x4 w4 = *reinterpret_cast<const f32x4*>(Pb + 512 + m * 16 + kg * 4);

    unsigned ah01 = pkhi(wa[0], wa[1]), ah23 = pkhi(wa[2], wa[3]);
    unsigned al01 = pkhi(wa[0] - trunc_bf(wa[0]), wa[1] - trunc_bf(wa[1]));
    unsigned al23 = pkhi(wa[2] - trunc_bf(wa[2]), wa[3] - trunc_bf(wa[3]));
    bf16x8 Af = mk8(ah01, ah23, al01, al23);      // [Ah | Al]

    unsigned g01 = pkhi(wg[0], wg[1]), g23 = pkhi(wg[2], wg[3]);
    bf16x8 Gf = mk8(g01, g23, g01, g23);          // [G | G]

    unsigned w401 = pkhi(w4[0], w4[1]), w423 = pkhi(w4[2], w4[3]);
    unsigned wl01 = pkhi(w4[0] - trunc_bf(w4[0]), w4[1] - trunc_bf(w4[1]));
    unsigned wl23 = pkhi(w4[2] - trunc_bf(w4[2]), w4[3] - trunc_bf(w4[3]));
    bf16x8 Wf = mk8(w401, w423, wl01, wl23);      // [W4h | W4l]

    f32x4 biasA = *reinterpret_cast<const f32x4*>(Pb + 768 + kg * 4);
    f32x4 biasG = *reinterpret_cast<const f32x4*>(Pb + 784 + kg * 4);
    f32x4 biasW = *reinterpret_cast<const f32x4*>(Pb + 800 + kg * 4);

    const f32x2* xb2 = reinterpret_cast<const f32x2*>(x + (size_t)b * NC * HW);
    f32x2*       ob2 = reinterpret_cast<f32x2*>(out + (size_t)b * NC * HW);

    // f32x2-unit offsets: channel kg*4+c, pixel-pair wib*128 + m (+ t*16)
    unsigned basep = (unsigned)wib * 128 + (unsigned)m;
    unsigned off0 = (unsigned)(kg * 4 + 0) * (HW / 2) + basep;
    unsigned off1 = (unsigned)(kg * 4 + 1) * (HW / 2) + basep;
    unsigned off2 = (unsigned)(kg * 4 + 2) * (HW / 2) + basep;
    unsigned off3 = (unsigned)(kg * 4 + 3) * (HW / 2) + basep;

    #pragma unroll
    for (int t = 0; t < 8; ++t) {
        f32x2 v0 = xb2[off0 + t * 16];
        f32x2 v1 = xb2[off1 + t * 16];
        f32x2 v2 = xb2[off2 + t * 16];
        f32x2 v3 = xb2[off3 + t * 16];

        f32x4 oA = tile16(v0.x, v1.x, v2.x, v3.x, Af, Gf, Wf, biasA, biasG, biasW);
        f32x4 oB = tile16(v0.y, v1.y, v2.y, v3.y, Af, Gf, Wf, biasA, biasG, biasW);

        f32x2 s0; s0.x = oA[0]; s0.y = oB[0];
        f32x2 s1; s1.x = oA[1]; s1.y = oB[1];
        f32x2 s2; s2.x = oA[2]; s2.y = oB[2];
        f32x2 s3; s3.x = oA[3]; s3.y = oB[3];
        __builtin_nontemporal_store(s0, &ob2[off0 + t * 16]);
        __builtin_nontemporal_store(s1, &ob2[off1 + t * 16]);
        __builtin_nontemporal_store(s2, &ob2[off2 + t * 16]);
        __builtin_nontemporal_store(s3, &ob2[off3 + t * 16]);
    }
}

extern "C" void kernel_launch(void* const* d_in, const int* in_sizes, int n_in,
                              void* d_out, int out_size, void* d_ws, size_t ws_size,
                              hipStream_t stream) {
    const float* x  = (const float*)d_in[0];
    const float* Wc = (const float*)d_in[1];
    const float* bc = (const float*)d_in[2];
    const float* W1 = (const float*)d_in[3];
    const float* b1 = (const float*)d_in[4];
    const float* W2 = (const float*)d_in[5];
    const float* b2 = (const float*)d_in[6];
    const float* W3 = (const float*)d_in[7];
    const float* b3 = (const float*)d_in[8];
    const float* W4 = (const float*)d_in[9];
    const float* b4 = (const float*)d_in[10];
    float* out = (float*)d_out;

    float* psum   = (float*)d_ws;                 // 128*16 floats
    float* pmax   = psum + NB * NC * NSEG;        // 128*16 floats
    float* params = pmax + NB * NC * NSEG;        // 8*816 floats

    k_reduce<<<NB * NC * NSEG, 256, 0, stream>>>(x, psum, pmax);
    k_params<<<NB, 256, 0, stream>>>(psum, pmax, Wc, bc, W1, b1, W2, b2,
                                     W3, b3, W4, b4, params);
    k_main<<<NB * 256, 256, 0, stream>>>(x, params, out);
}

// Round 10
// 69.484 us; speedup vs baseline: 2.1293x; 1.0145x over previous
//
#include <hip/hip_runtime.h>
#include <hip/hip_bf16.h>
#include <cmath>

#define HW 262144          // 512*512
#define NC 16
#define NB 8
#define NSEG 16
#define SEGSZ (HW / NSEG)  // 16384
#define EPS 1e-5f

typedef float f32x4 __attribute__((ext_vector_type(4)));
typedef float f32x2 __attribute__((ext_vector_type(2)));
typedef short bf16x8 __attribute__((ext_vector_type(8)));

// ---------------- pass 1: per-(b,c,seg) partial sum & max ----------------
__global__ __launch_bounds__(256) void k_reduce(const float* __restrict__ x,
                                                float* __restrict__ psum,
                                                float* __restrict__ pmax) {
    int plane = blockIdx.x / NSEG;
    int seg   = blockIdx.x - plane * NSEG;
    const float4* p = reinterpret_cast<const float4*>(
        x + (size_t)plane * HW + (size_t)seg * SEGSZ);
    int t = threadIdx.x;
    float s = 0.0f, m = -INFINITY;
    #pragma unroll
    for (int it = 0; it < SEGSZ / (256 * 4); ++it) {
        float4 v = p[it * 256 + t];
        s += (v.x + v.y) + (v.z + v.w);
        m = fmaxf(m, fmaxf(fmaxf(v.x, v.y), fmaxf(v.z, v.w)));
    }
    #pragma unroll
    for (int off = 32; off > 0; off >>= 1) {
        s += __shfl_down(s, off, 64);
        m = fmaxf(m, __shfl_down(m, off, 64));
    }
    __shared__ float ls[4], lm[4];
    int wid = t >> 6, lane = t & 63;
    if (lane == 0) { ls[wid] = s; lm[wid] = m; }
    __syncthreads();
    if (t == 0) {
        psum[blockIdx.x] = (ls[0] + ls[1]) + (ls[2] + ls[3]);
        pmax[blockIdx.x] = fmaxf(fmaxf(lm[0], lm[1]), fmaxf(lm[2], lm[3]));
    }
}

// ---------------- pass 2: fold per-batch matrices ----------------
// params layout per batch (816 floats), ALL row-major [o][i] at o*16+i:
// [0:256)   A  = W2*diag(1/(mean+eps))*Wc
// [256:512) G  = W3*diag(1/(max+eps))*W1
// [512:768) W4
// [768:784) abias   [784:800) gbias   [800:816) b4
__global__ __launch_bounds__(256) void k_params(
    const float* __restrict__ psum, const float* __restrict__ pmax,
    const float* __restrict__ Wc, const float* __restrict__ bc,
    const float* __restrict__ W1, const float* __restrict__ b1,
    const float* __restrict__ W2, const float* __restrict__ b2,
    const float* __restrict__ W3, const float* __restrict__ b3,
    const float* __restrict__ W4, const float* __restrict__ b4,
    float* __restrict__ params) {
    int b = blockIdx.x;
    int t = threadIdx.x;
    __shared__ float r2[NC], r4[NC], sWc[256], sW1[256], sW2[256], sW3[256];
    if (t < NC) {
        float s = 0.0f, m = -INFINITY;
        for (int k = 0; k < NSEG; ++k) {
            s += psum[(b * NC + t) * NSEG + k];
            m = fmaxf(m, pmax[(b * NC + t) * NSEG + k]);
        }
        r2[t] = 1.0f / (s * (1.0f / (float)HW) + EPS);
        r4[t] = 1.0f / (m + EPS);
    }
    sWc[t] = Wc[t]; sW1[t] = W1[t]; sW2[t] = W2[t]; sW3[t] = W3[t];
    __syncthreads();
    int o = t >> 4, i = t & 15;
    float accA = 0.0f, accG = 0.0f;
    #pragma unroll
    for (int c = 0; c < NC; ++c) {
        accA += sW2[o * NC + c] * r2[c] * sWc[c * NC + i];
        accG += sW3[o * NC + c] * r4[c] * sW1[c * NC + i];
    }
    float* P = params + b * 816;
    P[t]       = accA;          // A[o][i]
    P[256 + t] = accG;          // G[o][i]
    P[512 + t] = W4[t];         // W4[o][i]
    if (i == 0) {
        float ba = 0.0f, bg = 0.0f;
        #pragma unroll
        for (int c = 0; c < NC; ++c) {
            ba += sW2[o * NC + c] * r2[c] * bc[c];
            bg += sW3[o * NC + c] * r4[c] * b1[c];
        }
        P[768 + o] = ba + b2[o];
        P[784 + o] = bg + b3[o];
        P[800 + o] = b4[o];
    }
}

// sigmoid(tanh(x)): tanh via fast exp+rcp, sigmoid via odd Taylor on [-1,1]
__device__ __forceinline__ float gsig(float x) {
    float E = __expf(2.0f * x);
    float t = 1.0f - 2.0f * __builtin_amdgcn_rcpf(E + 1.0f);   // tanh(x)
    float t2 = t * t;
    return fmaf(t, fmaf(t2, fmaf(t2, 0.0020833333f, -0.0208333333f), 0.25f), 0.5f);
}

static __device__ __forceinline__ bf16x8 mk8(unsigned a, unsigned b,
                                             unsigned c, unsigned d) {
    union { unsigned u[4]; bf16x8 v; } r;
    r.u[0] = a; r.u[1] = b; r.u[2] = c; r.u[3] = d;
    return r.v;
}
static __device__ __forceinline__ unsigned pkhi(float x0, float x1) {
    return (__float_as_uint(x0) >> 16) | (__float_as_uint(x1) & 0xFFFF0000u);
}
static __device__ __forceinline__ float trunc_bf(float x) {
    return __uint_as_float(__float_as_uint(x) & 0xFFFF0000u);
}

// one 16ch x 16px MFMA tile: x0..x3 = this lane's 4 channels at its column
static __device__ __forceinline__ f32x4 tile16(float x0, float x1, float x2, float x3,
                                               bf16x8 Af, bf16x8 Gf, bf16x8 Wf,
                                               f32x4 biasA, f32x4 biasG, f32x4 biasW) {
    unsigned vh01 = pkhi(x0, x1), vh23 = pkhi(x2, x3);
    unsigned vl01 = pkhi(x0 - trunc_bf(x0), x1 - trunc_bf(x1));
    unsigned vl23 = pkhi(x2 - trunc_bf(x2), x3 - trunc_bf(x3));
    bf16x8 B1 = mk8(vh01, vh23, vl01, vl23);   // [vh ; vl]
    bf16x8 B2 = mk8(vl01, vl23, vh01, vh23);   // [vl ; vh]
    f32x4 wh = __builtin_amdgcn_mfma_f32_16x16x32_bf16(Af, B1, biasA, 0, 0, 0);
    wh = __builtin_amdgcn_mfma_f32_16x16x32_bf16(Af, B2, wh, 0, 0, 0);
    f32x4 gr = __builtin_amdgcn_mfma_f32_16x16x32_bf16(Gf, B1, biasG, 0, 0, 0);
    float u0 = fmaf(x0, gsig(wh[0]) + gsig(gr[0]), x0);
    float u1 = fmaf(x1, gsig(wh[1]) + gsig(gr[1]), x1);
    float u2 = fmaf(x2, gsig(wh[2]) + gsig(gr[2]), x2);
    float u3 = fmaf(x3, gsig(wh[3]) + gsig(gr[3]), x3);
    unsigned uh01 = pkhi(u0, u1), uh23 = pkhi(u2, u3);
    unsigned ul01 = pkhi(u0 - trunc_bf(u0), u1 - trunc_bf(u1));
    unsigned ul23 = pkhi(u2 - trunc_bf(u2), u3 - trunc_bf(u3));
    f32x4 o = __builtin_amdgcn_mfma_f32_16x16x32_bf16(Wf, mk8(uh01, uh23, ul01, ul23), biasW, 0, 0, 0);
    o = __builtin_amdgcn_mfma_f32_16x16x32_bf16(Wf, mk8(ul01, ul23, uh01, uh23), o, 0, 0, 0);
    return o;
}

// ---------------- pass 3: MFMA, f32x2 lanes -> 2 interleaved tiles --------
// Tile j column n <-> pixel 2n+j. Full 128B-line loads/stores per channel seg.
// asm pins: (a) weight frags/biases can't be rematerialized per-iteration,
// (b) prefetched next-iter loads can't be sunk back to their use.
__global__ __launch_bounds__(256) void k_main(const float* __restrict__ x,
                                              const float* __restrict__ params,
                                              float* __restrict__ out) {
    int b    = blockIdx.x >> 8;                                // 256 blocks/batch
    int wib  = ((blockIdx.x & 255) << 2) + (threadIdx.x >> 6); // wave in batch
    int lane = threadIdx.x & 63;
    int m  = lane & 15;
    int kg = lane >> 4;

    const float* Pb = params + b * 816;

    f32x4 wa = *reinterpret_cast<const f32x4*>(Pb + m * 16 + kg * 4);
    f32x4 wg = *reinterpret_cast<const f32x4*>(Pb + 256 + m * 16 + kg * 4);
    f32x4 w4 = *reinterpret_cast<const f32x4*>(Pb + 512 + m * 16 + kg * 4);

    unsigned ah01 = pkhi(wa[0], wa[1]), ah23 = pkhi(wa[2], wa[3]);
    unsigned al01 = pkhi(wa[0] - trunc_bf(wa[0]), wa[1] - trunc_bf(wa[1]));
    unsigned al23 = pkhi(wa[2] - trunc_bf(wa[2]), wa[3] - trunc_bf(wa[3]));
    bf16x8 Af = mk8(ah01, ah23, al01, al23);      // [Ah | Al]

    unsigned g01 = pkhi(wg[0], wg[1]), g23 = pkhi(wg[2], wg[3]);
    bf16x8 Gf = mk8(g01, g23, g01, g23);          // [G | G]

    unsigned w401 = pkhi(w4[0], w4[1]), w423 = pkhi(w4[2], w4[3]);
    unsigned wl01 = pkhi(w4[0] - trunc_bf(w4[0]), w4[1] - trunc_bf(w4[1]));
    unsigned wl23 = pkhi(w4[2] - trunc_bf(w4[2]), w4[3] - trunc_bf(w4[3]));
    bf16x8 Wf = mk8(w401, w423, wl01, wl23);      // [W4h | W4l]

    f32x4 biasA = *reinterpret_cast<const f32x4*>(Pb + 768 + kg * 4);
    f32x4 biasG = *reinterpret_cast<const f32x4*>(Pb + 784 + kg * 4);
    f32x4 biasW = *reinterpret_cast<const f32x4*>(Pb + 800 + kg * 4);

    // pin invariants in VGPRs — RA cannot rematerialize asm-defined values
    asm("" : "+v"(Af), "+v"(Gf), "+v"(Wf));
    asm("" : "+v"(biasA), "+v"(biasG), "+v"(biasW));

    const f32x2* xb2 = reinterpret_cast<const f32x2*>(x + (size_t)b * NC * HW);
    f32x2*       ob2 = reinterpret_cast<f32x2*>(out + (size_t)b * NC * HW);

    unsigned basep = (unsigned)wib * 128 + (unsigned)m;
    unsigned off0 = (unsigned)(kg * 4 + 0) * (HW / 2) + basep;
    unsigned off1 = (unsigned)(kg * 4 + 1) * (HW / 2) + basep;
    unsigned off2 = (unsigned)(kg * 4 + 2) * (HW / 2) + basep;
    unsigned off3 = (unsigned)(kg * 4 + 3) * (HW / 2) + basep;

    f32x2 v0 = xb2[off0], v1 = xb2[off1], v2 = xb2[off2], v3 = xb2[off3];

    #pragma unroll
    for (int t = 0; t < 8; ++t) {
        f32x2 n0, n1, n2, n3;
        if (t < 7) {
            n0 = xb2[off0 + (t + 1) * 16];
            n1 = xb2[off1 + (t + 1) * 16];
            n2 = xb2[off2 + (t + 1) * 16];
            n3 = xb2[off3 + (t + 1) * 16];
            // pin: loads stay issued here, overlapping this iter's compute
            asm("" : "+v"(n0), "+v"(n1), "+v"(n2), "+v"(n3));
        } else {
            n0 = v0; n1 = v1; n2 = v2; n3 = v3;
        }

        f32x4 oA = tile16(v0.x, v1.x, v2.x, v3.x, Af, Gf, Wf, biasA, biasG, biasW);
        f32x4 oB = tile16(v0.y, v1.y, v2.y, v3.y, Af, Gf, Wf, biasA, biasG, biasW);

        f32x2 s0; s0.x = oA[0]; s0.y = oB[0];
        f32x2 s1; s1.x = oA[1]; s1.y = oB[1];
        f32x2 s2; s2.x = oA[2]; s2.y = oB[2];
        f32x2 s3; s3.x = oA[3]; s3.y = oB[3];
        __builtin_nontemporal_store(s0, &ob2[off0 + t * 16]);
        __builtin_nontemporal_store(s1, &ob2[off1 + t * 16]);
        __builtin_nontemporal_store(s2, &ob2[off2 + t * 16]);
        __builtin_nontemporal_store(s3, &ob2[off3 + t * 16]);

        v0 = n0; v1 = n1; v2 = n2; v3 = n3;
    }
}

extern "C" void kernel_launch(void* const* d_in, const int* in_sizes, int n_in,
                              void* d_out, int out_size, void* d_ws, size_t ws_size,
                              hipStream_t stream) {
    const float* x  = (const float*)d_in[0];
    const float* Wc = (const float*)d_in[1];
    const float* bc = (const float*)d_in[2];
    const float* W1 = (const float*)d_in[3];
    const float* b1 = (const float*)d_in[4];
    const float* W2 = (const float*)d_in[5];
    const float* b2 = (const float*)d_in[6];
    const float* W3 = (const float*)d_in[7];
    const float* b3 = (const float*)d_in[8];
    const float* W4 = (const float*)d_in[9];
    const float* b4 = (const float*)d_in[10];
    float* out = (float*)d_out;

    float* psum   = (float*)d_ws;                 // 128*16 floats
    float* pmax   = psum + NB * NC * NSEG;        // 128*16 floats
    float* params = pmax + NB * NC * NSEG;        // 8*816 floats

    k_reduce<<<NB * NC * NSEG, 256, 0, stream>>>(x, psum, pmax);
    k_params<<<NB, 256, 0, stream>>>(psum, pmax, Wc, bc, W1, b1, W2, b2,
                                     W3, b3, W4, b4, params);
    k_main<<<NB * 256, 256, 0, stream>>>(x, params, out);
}